// Round 7
// baseline (496.942 us; speedup 1.0000x reference)
//
#include <hip/hip_runtime.h>
#include <hip/hip_bf16.h>

#define Sdim 4096
#define Ndim 32
#define Hdim 512
#define Mdim (Sdim * Ndim)

#define BM 128
#define BN 256
#define BK 64

#define SC 512              // context s-chunks
#define SCR (Sdim / SC)     // 8 rows per chunk

typedef __bf16 bf16x8 __attribute__((ext_vector_type(8)));
typedef float f32x4 __attribute__((ext_vector_type(4)));
typedef unsigned short ushort8v __attribute__((ext_vector_type(8)));

__device__ __forceinline__ void load_lds16(const void* g, void* l) {
    __builtin_amdgcn_global_load_lds(
        (const __attribute__((address_space(1))) void*)g,
        (__attribute__((address_space(3))) void*)l, 16, 0, 0);
}

__device__ __forceinline__ float ftanh(float x) {
    float e = __expf(2.f * x);
    return 1.f - 2.f / (e + 1.f);
}

// ---------------- merged: blocks [0,128): bias[n][c] = hidden[n]·Ww[c]+Wb+Ub
//                  blocks [128,384): U_w fp32 -> bf16 packed cvt
//                  block 0 also zeroes sums[] for k_sumexp's atomics
__global__ __launch_bounds__(256) void k_prep(
    const float* __restrict__ hidden, const float* __restrict__ Ww,
    const float* __restrict__ Wb, const float* __restrict__ Ubias,
    float* __restrict__ bias, const float* __restrict__ Uw,
    unsigned short* __restrict__ Ub16, float* __restrict__ sums) {
    const int t = threadIdx.x;
    if (blockIdx.x < 128) {
        if (blockIdx.x == 0 && t < Ndim) sums[t] = 0.f;
        const int w = t >> 6, lane = t & 63;
        const int cc = blockIdx.x * 4 + w;
        const float4 w0 = *(const float4*)(Ww + (size_t)cc * Hdim + lane * 8);
        const float4 w1 =
            *(const float4*)(Ww + (size_t)cc * Hdim + lane * 8 + 4);
        const float wb = Wb[cc] + Ubias[cc];
        for (int n = 0; n < Ndim; ++n) {
            const float4 h0 = *(const float4*)(hidden + n * Hdim + lane * 8);
            const float4 h1 =
                *(const float4*)(hidden + n * Hdim + lane * 8 + 4);
            float p = w0.x * h0.x + w0.y * h0.y + w0.z * h0.z + w0.w * h0.w +
                      w1.x * h1.x + w1.y * h1.y + w1.z * h1.z + w1.w * h1.w;
            p += __shfl_xor(p, 1);  p += __shfl_xor(p, 2);
            p += __shfl_xor(p, 4);  p += __shfl_xor(p, 8);
            p += __shfl_xor(p, 16); p += __shfl_xor(p, 32);
            if (lane == 0) bias[n * Hdim + cc] = p + wb;
        }
    } else {
        const int i = (blockIdx.x - 128) * 256 + t;
        float4 v = ((const float4*)Uw)[i];
        union { __hip_bfloat162 h[2]; ushort4 u; } r;
        r.h[0] = __float22bfloat162_rn(make_float2(v.x, v.y));
        r.h[1] = __float22bfloat162_rn(make_float2(v.z, v.w));
        ((ushort4*)Ub16)[i] = r.u;
    }
}

// ---------------- fused partial score (champion structure, R1/R5-verified):
// 128x256 tile, BK=64, single-buffer, 2 raw barriers/step, counted vmcnt(4),
// 144B-padded A rows, 8-chunk XOR-swizzled B staging.
// XCD-pairing block decode (R4: FETCH 267->140 MB, duration-neutral).
__global__ __launch_bounds__(512, 4) void k_gemm_score(
    const float* __restrict__ enc,          // [M, H] fp32
    const unsigned short* __restrict__ Ub,  // [H, H] bf16, row=out col
    const float* __restrict__ bias,         // [N, H]
    const float* __restrict__ vw,           // [H]
    float* __restrict__ scorep) {           // [2][N, S] partials
    __shared__ __align__(16) unsigned short Asm[BM][72];  // 144B rows (pad)
    __shared__ __align__(16) unsigned short Bsm[BN * BK]; // linear, swizzled
    __shared__ float ssm[4][BM];

    const int t = threadIdx.x;
    const int lane = t & 63;
    const int w = t >> 6;
    const int wM = w >> 2;
    const int wN = w & 3;
    const int c = lane & 15;
    const int q = lane >> 4;

    const int x = blockIdx.x;
    const int rowblk = (x & 7) | ((x >> 4) << 3);  // 0..1023
    const int colblk = (x >> 3) & 1;
    const int mBase = rowblk * BM;
    const int colBase = colblk * BN;

    // A staging: thread -> row t>>2, 16-float chunk t&3 (64B load)
    const int ar = t >> 2;
    const int aq = t & 3;
    const int asw = ((ar >> 3) & 1) << 1;  // XOR on 16B-chunk bit1
    const float4* arow =
        (const float4*)(enc + (size_t)(mBase + ar) * Hdim) + aq * 4;
    unsigned short* awr = &Asm[ar][((2 * aq) ^ asw) * 8];

    // B staging: 4 global_load_lds/thread; source chunk XOR-swizzled by col&7
    const int coff = lane >> 3;            // col within 8-col group
    const int bch = (lane & 7) ^ coff;     // pre-swizzled source chunk
    const unsigned short* bsrc =
        Ub + (size_t)(colBase + w * 8 + coff) * Hdim + bch * 8;
    unsigned short* bdst = Bsm + (w * 8) * BK;

    const int sA = ((c >> 3) & 1) << 1;  // A un-swizzle (lane const)
    const int sB = c & 7;                // B un-swizzle (lane const)

    f32x4 acc[4][4];
#pragma unroll
    for (int i = 0; i < 4; ++i)
#pragma unroll
        for (int j = 0; j < 4; ++j) acc[i][j] = (f32x4){0.f, 0.f, 0.f, 0.f};

    // prologue: A(0) in regs
    float4 a0 = *(const float4*)(arow + 0);
    float4 a1 = *(const float4*)(arow + 1);
    float4 a2 = *(const float4*)(arow + 2);
    float4 a3 = *(const float4*)(arow + 3);

#pragma unroll 1
    for (int kk = 0; kk < Hdim / BK; ++kk) {
        // barrier #1: all waves done reading LDS of step kk-1.
        asm volatile("" ::: "memory");
        __builtin_amdgcn_s_barrier();
        asm volatile("" ::: "memory");
        __builtin_amdgcn_sched_barrier(0);

        // issue B(kk): 4 x 1KB direct-to-LDS (oldest vmem ops this step)
#pragma unroll
        for (int g = 0; g < 4; ++g)
            load_lds16(bsrc + (size_t)g * 64 * Hdim + kk * BK,
                       bdst + g * 64 * BK);
        asm volatile("" ::: "memory");
        __builtin_amdgcn_sched_barrier(0);

        // cvt A(kk) regs -> LDS (compiler waits only the 4 A loads)
        union { __hip_bfloat162 h[4]; ushort8v v; } p0, p1;
        p0.h[0] = __float22bfloat162_rn(make_float2(a0.x, a0.y));
        p0.h[1] = __float22bfloat162_rn(make_float2(a0.z, a0.w));
        p0.h[2] = __float22bfloat162_rn(make_float2(a1.x, a1.y));
        p0.h[3] = __float22bfloat162_rn(make_float2(a1.z, a1.w));
        p1.h[0] = __float22bfloat162_rn(make_float2(a2.x, a2.y));
        p1.h[1] = __float22bfloat162_rn(make_float2(a2.z, a2.w));
        p1.h[2] = __float22bfloat162_rn(make_float2(a3.x, a3.y));
        p1.h[3] = __float22bfloat162_rn(make_float2(a3.z, a3.w));
        *(ushort8v*)awr = p0.v;
        *(ushort8v*)(awr + 8) = p1.v;

        // issue A(kk+1) prefetch (4 newest vmem ops; clamped tail reload
        // keeps the vmcnt count exact — kept live after the loop)
        const int kn = (kk < Hdim / BK - 1) ? kk + 1 : kk;
        const float4* ap = arow + kn * 16;
        a0 = ap[0]; a1 = ap[1]; a2 = ap[2]; a3 = ap[3];

        asm volatile("" ::: "memory");
        __builtin_amdgcn_sched_barrier(0);
        // wait B done + A-writes visible; A prefetch (4) stays in flight
        asm volatile("s_waitcnt vmcnt(4) lgkmcnt(0)" ::: "memory");
        __builtin_amdgcn_s_barrier();
        asm volatile("" ::: "memory");
        __builtin_amdgcn_sched_barrier(0);

        // compute: 2 k-halves of 16 MFMA (no h-unroll: VGPR <= 128 cap)
#pragma unroll 1
        for (int h = 0; h < 2; ++h) {
            bf16x8 af[4], bfr[4];
#pragma unroll
            for (int mi = 0; mi < 4; ++mi) {
                const int row = wM * 64 + mi * 16 + c;
                af[mi] =
                    *(const bf16x8*)&Asm[row][(((h << 2) | q) ^ sA) * 8];
            }
#pragma unroll
            for (int ni = 0; ni < 4; ++ni) {
                const int lc = wN * 64 + ni * 16 + c;
                bfr[ni] = *(const bf16x8*)&Bsm[lc * BK +
                                               (((h << 2) | q) ^ sB) * 8];
            }
#pragma unroll
            for (int mi = 0; mi < 4; ++mi)
#pragma unroll
                for (int ni = 0; ni < 4; ++ni)
                    acc[mi][ni] = __builtin_amdgcn_mfma_f32_16x16x32_bf16(
                        af[mi], bfr[ni], acc[mi][ni], 0, 0, 0);
        }
    }
    // keep tail prefetch live (rule #17): DCE would break the vmcnt(4) count
    asm volatile("" :: "v"(a0.x), "v"(a1.x), "v"(a2.x), "v"(a3.x));

    // epilogue: per-row partial of v·tanh(acc + bias)  (v_b cancels)
    float vcol[4];
#pragma unroll
    for (int ni = 0; ni < 4; ++ni)
        vcol[ni] = vw[colBase + wN * 64 + ni * 16 + c];

#pragma unroll
    for (int mi = 0; mi < 4; ++mi) {
#pragma unroll
        for (int reg = 0; reg < 4; ++reg) {
            const int rl = wM * 64 + mi * 16 + q * 4 + reg;
            const int n = rl & 31;  // mBase % 32 == 0
            float p = 0.f;
#pragma unroll
            for (int ni = 0; ni < 4; ++ni) {
                const int col = colBase + wN * 64 + ni * 16 + c;
                float e = acc[mi][ni][reg] + bias[n * Hdim + col];
                p += vcol[ni] * ftanh(e);
            }
            p += __shfl_xor(p, 1);
            p += __shfl_xor(p, 2);
            p += __shfl_xor(p, 4);
            p += __shfl_xor(p, 8);
            if (c == 0) ssm[wN][rl] = p;
        }
    }
    __syncthreads();
    if (t < BM) {
        const int m = mBase + t;
        const float s = ssm[0][t] + ssm[1][t] + ssm[2][t] + ssm[3][t];
        scorep[colblk * Mdim + (m & 31) * Sdim + (m >> 5)] = s;
    }
}

// ---------------- partial sum(exp(s0+s1)) per n, atomic accumulate.
// 128 blocks (4 per n) instead of 32: latency-bound kernel gets 4x the CUs.
// Scores are O(1): shift-invariant softmax needs no max subtraction.
__global__ __launch_bounds__(256) void k_sumexp(
    const float* __restrict__ scorep,  // [2][N][S] partials
    float* __restrict__ sums) {        // [N] sums (pre-zeroed in k_prep)
    const int b = blockIdx.x;          // 0..127
    const int n = b >> 2;
    const int i = (b & 3) * 256 + threadIdx.x;  // f4 index within row
    const int t = threadIdx.x;
    const float4 a = ((const float4*)(scorep + n * Sdim))[i];
    const float4 c = ((const float4*)(scorep + Mdim + n * Sdim))[i];
    float s = __expf(a.x + c.x) + __expf(a.y + c.y) + __expf(a.z + c.z) +
              __expf(a.w + c.w);
#pragma unroll
    for (int o = 32; o > 0; o >>= 1) s += __shfl_xor(s, o);
    __shared__ float red[4];
    if ((t & 63) == 0) red[t >> 6] = s;
    __syncthreads();
    if (t == 0) atomicAdd(&sums[n], red[0] + red[1] + red[2] + red[3]);
}

// ---------------- fused weights+context, column-owner layout, SC=512.
// Block sc owns the contiguous 512KB slab enc[8 s-rows][32n][512h]
// (512 blocks = 2 resident/CU: 2x the waves of the R6 version that was
// occupancy-starved at 1 block/CU). Thread t owns float4-columns
// {t + j*512, j<8}: every wave instruction reads contiguous 1KB, weight
// lookup is wave-uniform broadcast, accumulators are complete partials ->
// no reduction tree.
__global__ __launch_bounds__(512) void k_context(
    const float* __restrict__ enc, const float* __restrict__ scorep,
    const float* __restrict__ sums, float* __restrict__ out_w,
    float* __restrict__ part) {
    const int sc = blockIdx.x;     // 0..511
    const int s0 = sc * SCR;       // 8 rows
    const int t = threadIdx.x;

    __shared__ float wsm[SCR * Ndim];  // 8 x 32
    if (t < SCR * Ndim) {
        const int sl = t >> 5, n = t & 31;
        const int s = s0 + sl;
        const float sv = scorep[n * Sdim + s] + scorep[Mdim + n * Sdim + s];
        const float wv = __expf(sv) / sums[n];
        wsm[t] = wv;
        out_w[(size_t)s * Ndim + n] = wv;
    }
    __syncthreads();

    float4 acc[8];
#pragma unroll
    for (int j = 0; j < 8; ++j) acc[j] = (float4){0.f, 0.f, 0.f, 0.f};

#pragma unroll 2
    for (int s = 0; s < SCR; ++s) {
        const float4* row =
            (const float4*)enc + (size_t)(s0 + s) * (Ndim * Hdim / 4);
#pragma unroll
        for (int j = 0; j < 8; ++j) {
            const int idx = t + j * 512;             // f4 col in slab row
            const float wv = wsm[s * 32 + (idx >> 7)];  // n = idx/128, uniform
            const float4 e = row[idx];
            acc[j].x += wv * e.x; acc[j].y += wv * e.y;
            acc[j].z += wv * e.z; acc[j].w += wv * e.w;
        }
    }
    float4* po = (float4*)part + (size_t)sc * 4096;
#pragma unroll
    for (int j = 0; j < 8; ++j) po[t + j * 512] = acc[j];
}

// ---------------- reduce 512 partial chunks -> context [N,H]
__global__ __launch_bounds__(256) void k_ctx_reduce(
    const float* __restrict__ part, float* __restrict__ out) {
    const int b = blockIdx.x;      // 0..63
    const int t = threadIdx.x;
    const int isub = t >> 6;       // 0..3
    const int jo = t & 63;
    const int j4 = b * 64 + jo;    // f4 index 0..4095
    const float4* p = (const float4*)part;
    float4 s = {0.f, 0.f, 0.f, 0.f};
#pragma unroll 4
    for (int i = isub; i < SC; i += 4) {
        const float4 v = p[(size_t)i * 4096 + j4];
        s.x += v.x; s.y += v.y; s.z += v.z; s.w += v.w;
    }
    __shared__ __align__(16) float4 red[4][64];
    red[isub][jo] = s;
    __syncthreads();
    if (t < 64) {
        const float4 a = red[0][t], c = red[1][t], d = red[2][t],
                     e = red[3][t];
        float4 r;
        r.x = a.x + c.x + d.x + e.x;
        r.y = a.y + c.y + d.y + e.y;
        r.z = a.z + c.z + d.z + e.z;
        r.w = a.w + c.w + d.w + e.w;
        ((float4*)out)[b * 64 + t] = r;
    }
}

extern "C" void kernel_launch(void* const* d_in, const int* in_sizes, int n_in,
                              void* d_out, int out_size, void* d_ws,
                              size_t ws_size, hipStream_t stream) {
    const float* hidden = (const float*)d_in[0];
    const float* enc    = (const float*)d_in[1];
    const float* Ww     = (const float*)d_in[2];
    const float* Wb     = (const float*)d_in[3];
    const float* Uw     = (const float*)d_in[4];
    const float* Ubias  = (const float*)d_in[5];
    const float* vw     = (const float*)d_in[6];

    float* out = (float*)d_out;  // [0,16384): context; [16384,...): weights

    char* ws = (char*)d_ws;
    float* bias          = (float*)(ws);                         // 64 KB
    unsigned short* Ub16 = (unsigned short*)(ws + (64 << 10));   // 512 KB
    float* scorep        = (float*)(ws + (576 << 10));           // 2x512 KB
    float* sums          = (float*)(ws + (1600 << 10));          // 128 B
    float* part          = (float*)(ws + (1664 << 10));          // 8 MB

    k_prep<<<384, 256, 0, stream>>>(hidden, Ww, Wb, Ubias, bias, Uw, Ub16,
                                    sums);
    k_gemm_score<<<(Mdim / BM) * 2, 512, 0, stream>>>(enc, Ub16, bias, vw,
                                                      scorep);
    k_sumexp<<<128, 256, 0, stream>>>(scorep, sums);
    k_context<<<SC, 512, 0, stream>>>(enc, scorep, sums, out + Ndim * Hdim,
                                      part);
    k_ctx_reduce<<<64, 256, 0, stream>>>(part, out);
}

// Round 8
// 480.948 us; speedup vs baseline: 1.0333x; 1.0333x over previous
//
#include <hip/hip_runtime.h>
#include <hip/hip_bf16.h>

#define Sdim 4096
#define Ndim 32
#define Hdim 512
#define Mdim (Sdim * Ndim)

#define BM 128
#define BN 256
#define BK 64

typedef __bf16 bf16x8 __attribute__((ext_vector_type(8)));
typedef float f32x4 __attribute__((ext_vector_type(4)));
typedef unsigned short ushort8v __attribute__((ext_vector_type(8)));

__device__ __forceinline__ void load_lds16(const void* g, void* l) {
    __builtin_amdgcn_global_load_lds(
        (const __attribute__((address_space(1))) void*)g,
        (__attribute__((address_space(3))) void*)l, 16, 0, 0);
}

__device__ __forceinline__ float ftanh(float x) {
    float e = __expf(2.f * x);
    return 1.f - 2.f / (e + 1.f);
}

// ---------------- merged: blocks [0,128): bias[n][c] = hidden[n]·Ww[c]+Wb+Ub
//                  blocks [128,384): U_w fp32 -> bf16 packed cvt
__global__ __launch_bounds__(256) void k_prep(
    const float* __restrict__ hidden, const float* __restrict__ Ww,
    const float* __restrict__ Wb, const float* __restrict__ Ubias,
    float* __restrict__ bias, const float* __restrict__ Uw,
    unsigned short* __restrict__ Ub16) {
    const int t = threadIdx.x;
    if (blockIdx.x < 128) {
        const int w = t >> 6, lane = t & 63;
        const int cc = blockIdx.x * 4 + w;
        const float4 w0 = *(const float4*)(Ww + (size_t)cc * Hdim + lane * 8);
        const float4 w1 =
            *(const float4*)(Ww + (size_t)cc * Hdim + lane * 8 + 4);
        const float wb = Wb[cc] + Ubias[cc];
        for (int n = 0; n < Ndim; ++n) {
            const float4 h0 = *(const float4*)(hidden + n * Hdim + lane * 8);
            const float4 h1 =
                *(const float4*)(hidden + n * Hdim + lane * 8 + 4);
            float p = w0.x * h0.x + w0.y * h0.y + w0.z * h0.z + w0.w * h0.w +
                      w1.x * h1.x + w1.y * h1.y + w1.z * h1.z + w1.w * h1.w;
            p += __shfl_xor(p, 1);  p += __shfl_xor(p, 2);
            p += __shfl_xor(p, 4);  p += __shfl_xor(p, 8);
            p += __shfl_xor(p, 16); p += __shfl_xor(p, 32);
            if (lane == 0) bias[n * Hdim + cc] = p + wb;
        }
    } else {
        const int i = (blockIdx.x - 128) * 256 + t;
        float4 v = ((const float4*)Uw)[i];
        union { __hip_bfloat162 h[2]; ushort4 u; } r;
        r.h[0] = __float22bfloat162_rn(make_float2(v.x, v.y));
        r.h[1] = __float22bfloat162_rn(make_float2(v.z, v.w));
        ((ushort4*)Ub16)[i] = r.u;
    }
}

// ---------------- fused partial score (champion structure, R1/R5-verified):
// 128x256 tile, BK=64, single-buffer, 2 raw barriers/step, counted vmcnt(4),
// 144B-padded A rows, 8-chunk XOR-swizzled B staging.
// ONLY delta vs R5 champion: XCD-pairing block decode — blocks x and x+8
// land on the same XCD (round-robin %8) and share one A-panel -> the pair's
// second A read is a same-XCD L2 hit (~200cy) instead of HBM (~900cy).
__global__ __launch_bounds__(512, 4) void k_gemm_score(
    const float* __restrict__ enc,          // [M, H] fp32
    const unsigned short* __restrict__ Ub,  // [H, H] bf16, row=out col
    const float* __restrict__ bias,         // [N, H]
    const float* __restrict__ vw,           // [H]
    float* __restrict__ scorep) {           // [2][N, S] partials
    __shared__ __align__(16) unsigned short Asm[BM][72];  // 144B rows (pad)
    __shared__ __align__(16) unsigned short Bsm[BN * BK]; // linear, swizzled
    __shared__ float ssm[4][BM];

    const int t = threadIdx.x;
    const int lane = t & 63;
    const int w = t >> 6;
    const int wM = w >> 2;
    const int wN = w & 3;
    const int c = lane & 15;
    const int q = lane >> 4;

    const int x = blockIdx.x;
    const int rowblk = (x & 7) | ((x >> 4) << 3);  // 0..1023
    const int colblk = (x >> 3) & 1;
    const int mBase = rowblk * BM;
    const int colBase = colblk * BN;

    // A staging: thread -> row t>>2, 16-float chunk t&3 (64B load)
    const int ar = t >> 2;
    const int aq = t & 3;
    const int asw = ((ar >> 3) & 1) << 1;  // XOR on 16B-chunk bit1
    const float4* arow =
        (const float4*)(enc + (size_t)(mBase + ar) * Hdim) + aq * 4;
    unsigned short* awr = &Asm[ar][((2 * aq) ^ asw) * 8];

    // B staging: 4 global_load_lds/thread; source chunk XOR-swizzled by col&7
    const int coff = lane >> 3;            // col within 8-col group
    const int bch = (lane & 7) ^ coff;     // pre-swizzled source chunk
    const unsigned short* bsrc =
        Ub + (size_t)(colBase + w * 8 + coff) * Hdim + bch * 8;
    unsigned short* bdst = Bsm + (w * 8) * BK;

    const int sA = ((c >> 3) & 1) << 1;  // A un-swizzle (lane const)
    const int sB = c & 7;                // B un-swizzle (lane const)

    f32x4 acc[4][4];
#pragma unroll
    for (int i = 0; i < 4; ++i)
#pragma unroll
        for (int j = 0; j < 4; ++j) acc[i][j] = (f32x4){0.f, 0.f, 0.f, 0.f};

    // prologue: A(0) in regs
    float4 a0 = *(const float4*)(arow + 0);
    float4 a1 = *(const float4*)(arow + 1);
    float4 a2 = *(const float4*)(arow + 2);
    float4 a3 = *(const float4*)(arow + 3);

#pragma unroll 1
    for (int kk = 0; kk < Hdim / BK; ++kk) {
        // barrier #1: all waves done reading LDS of step kk-1.
        asm volatile("" ::: "memory");
        __builtin_amdgcn_s_barrier();
        asm volatile("" ::: "memory");
        __builtin_amdgcn_sched_barrier(0);

        // issue B(kk): 4 x 1KB direct-to-LDS (oldest vmem ops this step)
#pragma unroll
        for (int g = 0; g < 4; ++g)
            load_lds16(bsrc + (size_t)g * 64 * Hdim + kk * BK,
                       bdst + g * 64 * BK);
        asm volatile("" ::: "memory");
        __builtin_amdgcn_sched_barrier(0);

        // cvt A(kk) regs -> LDS (compiler waits only the 4 A loads)
        union { __hip_bfloat162 h[4]; ushort8v v; } p0, p1;
        p0.h[0] = __float22bfloat162_rn(make_float2(a0.x, a0.y));
        p0.h[1] = __float22bfloat162_rn(make_float2(a0.z, a0.w));
        p0.h[2] = __float22bfloat162_rn(make_float2(a1.x, a1.y));
        p0.h[3] = __float22bfloat162_rn(make_float2(a1.z, a1.w));
        p1.h[0] = __float22bfloat162_rn(make_float2(a2.x, a2.y));
        p1.h[1] = __float22bfloat162_rn(make_float2(a2.z, a2.w));
        p1.h[2] = __float22bfloat162_rn(make_float2(a3.x, a3.y));
        p1.h[3] = __float22bfloat162_rn(make_float2(a3.z, a3.w));
        *(ushort8v*)awr = p0.v;
        *(ushort8v*)(awr + 8) = p1.v;

        // issue A(kk+1) prefetch (4 newest vmem ops; clamped tail reload
        // keeps the vmcnt count exact — kept live after the loop)
        const int kn = (kk < Hdim / BK - 1) ? kk + 1 : kk;
        const float4* ap = arow + kn * 16;
        a0 = ap[0]; a1 = ap[1]; a2 = ap[2]; a3 = ap[3];

        asm volatile("" ::: "memory");
        __builtin_amdgcn_sched_barrier(0);
        // wait B done + A-writes visible; A prefetch (4) stays in flight
        asm volatile("s_waitcnt vmcnt(4) lgkmcnt(0)" ::: "memory");
        __builtin_amdgcn_s_barrier();
        asm volatile("" ::: "memory");
        __builtin_amdgcn_sched_barrier(0);

        // compute: 2 k-halves of 16 MFMA (no h-unroll: VGPR <= 128 cap)
#pragma unroll 1
        for (int h = 0; h < 2; ++h) {
            bf16x8 af[4], bfr[4];
#pragma unroll
            for (int mi = 0; mi < 4; ++mi) {
                const int row = wM * 64 + mi * 16 + c;
                af[mi] =
                    *(const bf16x8*)&Asm[row][(((h << 2) | q) ^ sA) * 8];
            }
#pragma unroll
            for (int ni = 0; ni < 4; ++ni) {
                const int lc = wN * 64 + ni * 16 + c;
                bfr[ni] = *(const bf16x8*)&Bsm[lc * BK +
                                               (((h << 2) | q) ^ sB) * 8];
            }
#pragma unroll
            for (int mi = 0; mi < 4; ++mi)
#pragma unroll
                for (int ni = 0; ni < 4; ++ni)
                    acc[mi][ni] = __builtin_amdgcn_mfma_f32_16x16x32_bf16(
                        af[mi], bfr[ni], acc[mi][ni], 0, 0, 0);
        }
    }
    // keep tail prefetch live (rule #17): DCE would break the vmcnt(4) count
    asm volatile("" :: "v"(a0.x), "v"(a1.x), "v"(a2.x), "v"(a3.x));

    // epilogue: per-row partial of v·tanh(acc + bias)  (v_b cancels)
    float vcol[4];
#pragma unroll
    for (int ni = 0; ni < 4; ++ni)
        vcol[ni] = vw[colBase + wN * 64 + ni * 16 + c];

#pragma unroll
    for (int mi = 0; mi < 4; ++mi) {
#pragma unroll
        for (int reg = 0; reg < 4; ++reg) {
            const int rl = wM * 64 + mi * 16 + q * 4 + reg;
            const int n = rl & 31;  // mBase % 32 == 0
            float p = 0.f;
#pragma unroll
            for (int ni = 0; ni < 4; ++ni) {
                const int col = colBase + wN * 64 + ni * 16 + c;
                float e = acc[mi][ni][reg] + bias[n * Hdim + col];
                p += vcol[ni] * ftanh(e);
            }
            p += __shfl_xor(p, 1);
            p += __shfl_xor(p, 2);
            p += __shfl_xor(p, 4);
            p += __shfl_xor(p, 8);
            if (c == 0) ssm[wN][rl] = p;
        }
    }
    __syncthreads();
    if (t < BM) {
        const int m = mBase + t;
        const float s = ssm[0][t] + ssm[1][t] + ssm[2][t] + ssm[3][t];
        scorep[colblk * Mdim + (m & 31) * Sdim + (m >> 5)] = s;
    }
}

// ---------------- 1/sum(exp(s0+s1)) per n. Scores are O(1): shift-invariant
// softmax needs no max subtraction here (no overflow possible).
__global__ __launch_bounds__(256) void k_sumexp(
    const float* __restrict__ scorep,  // [2][N][S] partials
    float* __restrict__ sums) {        // [N] inverse sums
    const int n = blockIdx.x;
    const int t = threadIdx.x;
    const int w = t >> 6;
    const float4* p0 = (const float4*)(scorep + n * Sdim);
    const float4* p1 = (const float4*)(scorep + Mdim + n * Sdim);
    float s = 0.f;
    for (int i = t; i < Sdim / 4; i += 256) {
        const float4 a = p0[i], b = p1[i];
        s += __expf(a.x + b.x) + __expf(a.y + b.y) + __expf(a.z + b.z) +
             __expf(a.w + b.w);
    }
#pragma unroll
    for (int o = 32; o > 0; o >>= 1) s += __shfl_xor(s, o);
    __shared__ float red[4];
    if ((t & 63) == 0) red[w] = s;
    __syncthreads();
    if (t == 0) sums[n] = 1.f / (red[0] + red[1] + red[2] + red[3]);
}

// ---------------- fused weights+context (R5 champion tail). 32 S-chunks of
// 128 -> grid 1024 (4 blocks/CU), part only 2 MB.
__global__ __launch_bounds__(512) void k_context(
    const float* __restrict__ enc, const float* __restrict__ scorep,
    const float* __restrict__ sums, float* __restrict__ out_w,
    float* __restrict__ part) {
    const int n = blockIdx.x & 31;
    const int sc = blockIdx.x >> 5;  // 0..31
    const int s0 = sc * 128;
    const int t = threadIdx.x;
    const int g = t >> 6;    // 0..7: row slice
    const int lane = t & 63;
    const int h0 = lane * 8;

    __shared__ float wsm[128];
    if (t < 128) {
        const int s = s0 + t;
        const float sv = scorep[n * Sdim + s] + scorep[Mdim + n * Sdim + s];
        const float wv = __expf(sv) * sums[n];
        wsm[t] = wv;
        out_w[(size_t)s * Ndim + n] = wv;
    }
    __syncthreads();

    float4 c0 = {0.f, 0.f, 0.f, 0.f}, c1 = {0.f, 0.f, 0.f, 0.f};
#pragma unroll 4
    for (int it = 0; it < 16; ++it) {
        const int s = s0 + it * 8 + g;
        const float wv = wsm[it * 8 + g];
        const float* e = enc + ((size_t)s * Ndim + n) * Hdim + h0;
        const float4 e0 = *(const float4*)e;
        const float4 e1 = *(const float4*)(e + 4);
        c0.x += wv * e0.x; c0.y += wv * e0.y;
        c0.z += wv * e0.z; c0.w += wv * e0.w;
        c1.x += wv * e1.x; c1.y += wv * e1.y;
        c1.z += wv * e1.z; c1.w += wv * e1.w;
    }
    __shared__ __align__(16) float4 red[7][128];
    if (g > 0) { red[g - 1][lane * 2] = c0; red[g - 1][lane * 2 + 1] = c1; }
    __syncthreads();
    if (g == 0) {
#pragma unroll
        for (int i = 0; i < 7; ++i) {
            const float4 b0 = red[i][lane * 2];
            const float4 b1 = red[i][lane * 2 + 1];
            c0.x += b0.x; c0.y += b0.y; c0.z += b0.z; c0.w += b0.w;
            c1.x += b1.x; c1.y += b1.y; c1.z += b1.z; c1.w += b1.w;
        }
        float* o = part + (size_t)(sc * 32 + n) * Hdim + h0;
        *(float4*)o = c0;
        *(float4*)(o + 4) = c1;
    }
}

// ---------------- reduce 32 partial chunks -> context [N,H]
__global__ __launch_bounds__(256) void k_ctx_reduce(
    const float* __restrict__ part, float* __restrict__ out) {
    const int j = blockIdx.x * 256 + threadIdx.x;  // float4 index, 4096 total
    float4 s = {0.f, 0.f, 0.f, 0.f};
    for (int i = 0; i < 32; ++i) {
        const float4 v = ((const float4*)part)[i * 4096 + j];
        s.x += v.x; s.y += v.y; s.z += v.z; s.w += v.w;
    }
    ((float4*)out)[j] = s;
}

extern "C" void kernel_launch(void* const* d_in, const int* in_sizes, int n_in,
                              void* d_out, int out_size, void* d_ws,
                              size_t ws_size, hipStream_t stream) {
    const float* hidden = (const float*)d_in[0];
    const float* enc    = (const float*)d_in[1];
    const float* Ww     = (const float*)d_in[2];
    const float* Wb     = (const float*)d_in[3];
    const float* Uw     = (const float*)d_in[4];
    const float* Ubias  = (const float*)d_in[5];
    const float* vw     = (const float*)d_in[6];

    float* out = (float*)d_out;  // [0,16384): context; [16384,...): weights

    char* ws = (char*)d_ws;
    float* bias          = (float*)(ws);                         // 64 KB
    unsigned short* Ub16 = (unsigned short*)(ws + (64 << 10));   // 512 KB
    float* scorep        = (float*)(ws + (576 << 10));           // 2x512 KB
    float* sums          = (float*)(ws + (1600 << 10));          // 128 B
    float* part          = (float*)(ws + (1664 << 10));          // 2 MB

    k_prep<<<384, 256, 0, stream>>>(hidden, Ww, Wb, Ubias, bias, Uw, Ub16);
    k_gemm_score<<<(Mdim / BM) * 2, 512, 0, stream>>>(enc, Ub16, bias, vw,
                                                      scorep);
    k_sumexp<<<Ndim, 256, 0, stream>>>(scorep, sums);
    k_context<<<Ndim * (Sdim / 128), 512, 0, stream>>>(enc, scorep, sums,
                                                       out + Ndim * Hdim, part);
    k_ctx_reduce<<<16, 256, 0, stream>>>(part, out);
}